// Round 8
// baseline (413.469 us; speedup 1.0000x reference)
//
#include <hip/hip_runtime.h>
#include <hip/hip_bf16.h>
#include <cstdint>

// Exphormer attention, MI355X.
// K1 convert weights (fp32 -> bf16 hi/lo) + dst histogram ->
// K2 scan1 + scanB (CSR offsets/cursors) ->
// K3 fused QKV projection (bf16 MFMA, weight-split) ->
// K4 edge kernel: E proj (MFMA) + score + CSR scatter.
//    E exchange split into 2 half-tiles (f32, 17.4 KB LDS) -> 8 blocks/CU
//    occupancy for the latency-bound Q/K random gather epilogue ->
// K5 gather: out[dst] = sum score * V[src]  (f32x4, 32 thr/node, 8-deep unroll)

typedef float  f32x4  __attribute__((ext_vector_type(4)));
typedef short  bf16x8 __attribute__((ext_vector_type(8)));
typedef int    i32x4  __attribute__((ext_vector_type(4)));

#define AP 136   // A-tile row stride (bf16 elems): 64x136x2 = 17408 B
#define EP 132   // E half-tile row stride (f32):   32x132x4 = 16896 B

__device__ __forceinline__ short f2bf(float f) {
    union { float f; uint32_t u; } v; v.f = f;
    uint32_t r = v.u + 0x7FFFu + ((v.u >> 16) & 1u);   // RNE
    return (short)(r >> 16);
}
__device__ __forceinline__ float bf2f(short s) {
    union { uint32_t u; float f; } v; v.u = ((uint32_t)(uint16_t)s) << 16;
    return v.f;
}
__device__ __forceinline__ int cvt2(float a, float b) {
    float2 t; t.x = a; t.y = b;
    __hip_bfloat162 h = __float22bfloat162_rn(t);
    int r; __builtin_memcpy(&r, &h, 4);
    return r;
}
// non-temporal 16B load (streaming data: don't pollute caches)
__device__ __forceinline__ float4 ntload4(const float* p) {
    i32x4 r = __builtin_nontemporal_load((const i32x4*)p);
    float4 f; __builtin_memcpy(&f, &r, 16);
    return f;
}

// ---------------- K1: weight conversion + dst histogram ----------------
// Wall rows: [0:128)=Wq, [128:256)=Wk, [256:384)=Wv, [384:512)=We
__global__ __launch_bounds__(256) void convert_weights(
        const float* __restrict__ Wq, const float* __restrict__ bq,
        const float* __restrict__ Wk, const float* __restrict__ bk,
        const float* __restrict__ We, const float* __restrict__ be,
        const float* __restrict__ Wv, const float* __restrict__ bv,
        const int* __restrict__ dstp, int NE,
        short* __restrict__ Whi, short* __restrict__ Wlo, float* __restrict__ ball,
        int* __restrict__ counts) {
    int idx = blockIdx.x * 256 + threadIdx.x;     // 0..65535
    int wrow = idx >> 7;
    int k = idx & 127;
    int which = wrow >> 7;
    int r = wrow & 127;
    const float* Wsrc = which == 0 ? Wq : which == 1 ? Wk : which == 2 ? Wv : We;
    float f = Wsrc[r * 128 + k];
    short hi = f2bf(f);
    short lo = f2bf(f - bf2f(hi));
    Whi[idx] = hi; Wlo[idx] = lo;
    if (idx < 512) {
        int wh = idx >> 7; int rr = idx & 127;
        const float* bsrc = wh == 0 ? bq : wh == 1 ? bk : wh == 2 ? bv : be;
        ball[idx] = bsrc[rr];
    }
    // fused dst histogram (grid-stride over edges)
    for (int i = idx; i < NE; i += 65536)
        atomicAdd(&counts[dstp[i]], 1);
}

// ---------------- K2: CSR scans ----------------
__global__ __launch_bounds__(1024) void scan1_kernel(const int* __restrict__ counts,
                                                     int* __restrict__ incl,
                                                     int* __restrict__ partials, int n) {
    __shared__ int sh[1024];
    int t = threadIdx.x;
    int i = blockIdx.x * 1024 + t;
    sh[t] = (i < n) ? counts[i] : 0;
    for (int off = 1; off < 1024; off <<= 1) {
        __syncthreads();
        int xv = (t >= off) ? sh[t - off] : 0;
        __syncthreads();
        sh[t] += xv;
    }
    __syncthreads();
    if (i < n) incl[i] = sh[t];
    if (t == 1023) partials[blockIdx.x] = sh[1023];
}

// fused scan2+scan3: each block redundantly prefix-sums the (<=64) partials,
// then finalizes its segment of offsets + cursors.
__global__ __launch_bounds__(1024) void scanB_kernel(const int* __restrict__ counts,
                                                     int* __restrict__ offsets,
                                                     int* __restrict__ cursors,
                                                     const int* __restrict__ partials,
                                                     int n, int total) {
    int pbase = 0;
    for (int b = 0; b < (int)blockIdx.x; ++b) pbase += partials[b];
    int i = blockIdx.x * 1024 + threadIdx.x;
    if (i < n) {
        int off = offsets[i] - counts[i] + pbase;
        offsets[i] = off;
        cursors[i] = off;
    } else if (i == n) {
        offsets[n] = total;
    }
}

// ---------------- K3: fused QKV projection ----------------
__global__ __launch_bounds__(256, 4) void qkv_kernel(
        const float* __restrict__ x,
        const short* __restrict__ Whi, const short* __restrict__ Wlo,
        const float* __restrict__ ball,
        float* __restrict__ Qb, float* __restrict__ Kb, float* __restrict__ Vb,
        int N) {
    __shared__ char lds[64 * AP * 2];
    const int t = threadIdx.x;
    const int m0 = blockIdx.x * 64;

#pragma unroll
    for (int i = 0; i < 4; ++i) {
        int g = t + i * 256;
        int row = g >> 4, c8 = g & 15;
        int grow = m0 + row;
        float4 f0 = {0.f,0.f,0.f,0.f}, f1 = {0.f,0.f,0.f,0.f};
        if (grow < N) {
            const float* p = x + (size_t)grow * 128 + c8 * 8;
            f0 = ntload4(p); f1 = ntload4(p + 4);
        }
        int4 v;
        v.x = cvt2(f0.x, f0.y); v.y = cvt2(f0.z, f0.w);
        v.z = cvt2(f1.x, f1.y); v.w = cvt2(f1.z, f1.w);
        *(int4*)(lds + row * (AP * 2) + c8 * 16) = v;
    }
    __syncthreads();

    const int w = t >> 6, lane = t & 63;
    const int r16 = lane & 15, g16 = lane >> 4;
    const int cb = w * 32;

    for (int ct = 0; ct < 3; ++ct) {
        const int colbase = ct * 128;
        f32x4 acc[4][2];
#pragma unroll
        for (int m = 0; m < 4; ++m)
#pragma unroll
            for (int n = 0; n < 2; ++n) acc[m][n] = (f32x4){0.f,0.f,0.f,0.f};

#pragma unroll
        for (int ks = 0; ks < 4; ++ks) {
            bf16x8 a[4];
#pragma unroll
            for (int m = 0; m < 4; ++m)
                a[m] = *(const bf16x8*)(lds + (m * 16 + r16) * (AP * 2) + ks * 64 + g16 * 16);
            bf16x8 bh2[2], bl2[2];
#pragma unroll
            for (int n = 0; n < 2; ++n) {
                int colg = colbase + cb + n * 16 + r16;
                bh2[n] = *(const bf16x8*)(Whi + colg * 128 + ks * 32 + g16 * 8);
                bl2[n] = *(const bf16x8*)(Wlo + colg * 128 + ks * 32 + g16 * 8);
            }
#pragma unroll
            for (int m = 0; m < 4; ++m)
#pragma unroll
                for (int n = 0; n < 2; ++n) {
                    acc[m][n] = __builtin_amdgcn_mfma_f32_16x16x32_bf16(a[m], bh2[n], acc[m][n], 0, 0, 0);
                    acc[m][n] = __builtin_amdgcn_mfma_f32_16x16x32_bf16(a[m], bl2[n], acc[m][n], 0, 0, 0);
                }
        }
        float bias[2];
#pragma unroll
        for (int n = 0; n < 2; ++n) bias[n] = ball[colbase + cb + n * 16 + r16];

        float* outb = ct == 0 ? Qb : ct == 1 ? Kb : Vb;
#pragma unroll
        for (int m = 0; m < 4; ++m) {
            int grow = m0 + m * 16 + g16 * 4;
#pragma unroll
            for (int r = 0; r < 4; ++r) {
                if (grow + r < N) {
#pragma unroll
                    for (int n = 0; n < 2; ++n)
                        outb[(size_t)(grow + r) * 128 + cb + n * 16 + r16] = acc[m][n][r] + bias[n];
                }
            }
        }
    }
}

// ---------------- K4: edge kernel ----------------
// Two-phase E exchange keeps LDS at 17.4 KB -> 8 blocks/CU (~100% occupancy)
// so the latency-bound Q/K random gather epilogue hides under many waves.
__global__ __launch_bounds__(256) void edge_kernel(
        const float* __restrict__ ea,
        const int* __restrict__ srcp, const int* __restrict__ dstp,
        const short* __restrict__ Whi, const short* __restrict__ Wlo,
        const float* __restrict__ ball,
        const float* __restrict__ Qb, const float* __restrict__ Kb,
        float* __restrict__ scores, int* __restrict__ cursors,
        int2* __restrict__ ebuf, int NE) {
    __shared__ char lds[64 * AP * 2];             // 17408 B: A-tile, then E half-tile
    const int t = threadIdx.x;
    const int e0 = blockIdx.x * 64;

    // ---- top: edge indices + fused CSR scatter (cheap, 4 ints/thread) ----
    int sArr[2], dArr[2];
#pragma unroll
    for (int it = 0; it < 2; ++it) {
        int task = t + it * 256;                  // 0..511
        int el = task >> 3, h = task & 7;
        int eg = e0 + el;
        bool ok = eg < NE;
        int s = ok ? srcp[eg] : 0;
        int d = ok ? dstp[eg] : 0;
        sArr[it] = s; dArr[it] = d;
        if (ok && h == 0) {
            int pos = atomicAdd(&cursors[d], 1);
            int2 v; v.x = s * 128; v.y = eg * 8;
            ebuf[pos] = v;
        }
    }

    // ---- stage ea tile -> bf16 LDS ----
#pragma unroll
    for (int i = 0; i < 4; ++i) {
        int g = t + i * 256;
        int row = g >> 4, c8 = g & 15;
        int grow = e0 + row;
        float4 f0 = {0.f,0.f,0.f,0.f}, f1 = {0.f,0.f,0.f,0.f};
        if (grow < NE) {
            const float* p = ea + (size_t)grow * 128 + c8 * 8;
            f0 = ntload4(p); f1 = ntload4(p + 4);
        }
        int4 v;
        v.x = cvt2(f0.x, f0.y); v.y = cvt2(f0.z, f0.w);
        v.z = cvt2(f1.x, f1.y); v.w = cvt2(f1.z, f1.w);
        *(int4*)(lds + row * (AP * 2) + c8 * 16) = v;
    }
    __syncthreads();

    const int w = t >> 6, lane = t & 63;
    const int r16 = lane & 15, g16 = lane >> 4;
    const int cb = w * 32;

    f32x4 acc[4][2];
#pragma unroll
    for (int m = 0; m < 4; ++m)
#pragma unroll
        for (int n = 0; n < 2; ++n) acc[m][n] = (f32x4){0.f,0.f,0.f,0.f};

#pragma unroll
    for (int ks = 0; ks < 4; ++ks) {
        bf16x8 a[4];
#pragma unroll
        for (int m = 0; m < 4; ++m)
            a[m] = *(const bf16x8*)(lds + (m * 16 + r16) * (AP * 2) + ks * 64 + g16 * 16);
        bf16x8 bh2[2], bl2[2];
#pragma unroll
        for (int n = 0; n < 2; ++n) {
            int colg = 384 + cb + n * 16 + r16;   // We rows
            bh2[n] = *(const bf16x8*)(Whi + colg * 128 + ks * 32 + g16 * 8);
            bl2[n] = *(const bf16x8*)(Wlo + colg * 128 + ks * 32 + g16 * 8);
        }
#pragma unroll
        for (int m = 0; m < 4; ++m)
#pragma unroll
            for (int n = 0; n < 2; ++n) {
                acc[m][n] = __builtin_amdgcn_mfma_f32_16x16x32_bf16(a[m], bh2[n], acc[m][n], 0, 0, 0);
                acc[m][n] = __builtin_amdgcn_mfma_f32_16x16x32_bf16(a[m], bl2[n], acc[m][n], 0, 0, 0);
            }
    }
    float bias[2];
#pragma unroll
    for (int n = 0; n < 2; ++n) bias[n] = ball[384 + cb + n * 16 + r16];

    float* e_lds = (float*)lds;                   // reused as f32 E half-tile [32][EP]

    // ---- two phases: {write E rows, score epilogue} for edges 0-31, then 32-63 ----
#pragma unroll
    for (int ph = 0; ph < 2; ++ph) {
        __syncthreads();                          // prev phase (or A-tile reads) done
#pragma unroll
        for (int mm = 0; mm < 2; ++mm) {
            int m = ph * 2 + mm;
#pragma unroll
            for (int n = 0; n < 2; ++n)
#pragma unroll
                for (int r = 0; r < 4; ++r) {
                    int rloc = mm * 16 + g16 * 4 + r;       // 0..31
                    int col = cb + n * 16 + r16;
                    e_lds[rloc * EP + col] = acc[m][n][r] + bias[n];
                }
        }
        __syncthreads();

        // epilogue for this half: one task per thread
        int el = t >> 3, h = t & 7;               // el 0..31 local
        int eg = e0 + ph * 32 + el;
        if (eg < NE) {
            int s = sArr[ph], d = dArr[ph];
            const f32x4* Kp = (const f32x4*)(Kb + (size_t)s * 128 + h * 16);
            const f32x4* Qp = (const f32x4*)(Qb + (size_t)d * 128 + h * 16);
            float dot = 0.f;
#pragma unroll
            for (int j = 0; j < 4; ++j) {
                f32x4 ev = *(const f32x4*)(e_lds + el * EP + h * 16 + j * 4);
                f32x4 kq = Kp[j] * Qp[j];
                dot += ev[0] * kq[0] + ev[1] * kq[1] + ev[2] * kq[2] + ev[3] * kq[3];
            }
            float sv = fminf(fmaxf(dot * 0.25f, -5.0f), 5.0f);
            scores[(size_t)eg * 8 + h] = __expf(sv);
        }
    }
}

// ---------------- K5: gather/aggregate ----------------
// 32 threads per node (f32x4 per thread), 8 nodes per block, 8-deep unroll.
__global__ __launch_bounds__(256) void gather_kernel(
        const int* __restrict__ offsets, const int2* __restrict__ eb,
        const float* __restrict__ scores, const float* __restrict__ Vb,
        float* __restrict__ out, int N) {
    int node = blockIdx.x * 8 + (threadIdx.x >> 5);
    int c4 = threadIdx.x & 31;                    // float4 slot: cols [c4*4, c4*4+4)
    if (node >= N) return;
    int h = c4 >> 2;                              // head for these 4 cols
    int beg = offsets[node], end = offsets[node + 1];
    f32x4 a0 = {0.f,0.f,0.f,0.f}, a1 = a0, a2 = a0, a3 = a0;
    int j = beg;
    for (; j + 8 <= end; j += 8) {
        int2 e0 = eb[j],     e1 = eb[j + 1], e2 = eb[j + 2], e3 = eb[j + 3];
        int2 e4 = eb[j + 4], e5 = eb[j + 5], e6 = eb[j + 6], e7 = eb[j + 7];
        f32x4 v0 = *(const f32x4*)(Vb + e0.x + c4 * 4);
        f32x4 v1 = *(const f32x4*)(Vb + e1.x + c4 * 4);
        f32x4 v2 = *(const f32x4*)(Vb + e2.x + c4 * 4);
        f32x4 v3 = *(const f32x4*)(Vb + e3.x + c4 * 4);
        f32x4 v4 = *(const f32x4*)(Vb + e4.x + c4 * 4);
        f32x4 v5 = *(const f32x4*)(Vb + e5.x + c4 * 4);
        f32x4 v6 = *(const f32x4*)(Vb + e6.x + c4 * 4);
        f32x4 v7 = *(const f32x4*)(Vb + e7.x + c4 * 4);
        a0 += scores[e0.y + h] * v0;
        a1 += scores[e1.y + h] * v1;
        a2 += scores[e2.y + h] * v2;
        a3 += scores[e3.y + h] * v3;
        a0 += scores[e4.y + h] * v4;
        a1 += scores[e5.y + h] * v5;
        a2 += scores[e6.y + h] * v6;
        a3 += scores[e7.y + h] * v7;
    }
    for (; j + 4 <= end; j += 4) {
        int2 e0 = eb[j], e1 = eb[j + 1], e2 = eb[j + 2], e3 = eb[j + 3];
        f32x4 v0 = *(const f32x4*)(Vb + e0.x + c4 * 4);
        f32x4 v1 = *(const f32x4*)(Vb + e1.x + c4 * 4);
        f32x4 v2 = *(const f32x4*)(Vb + e2.x + c4 * 4);
        f32x4 v3 = *(const f32x4*)(Vb + e3.x + c4 * 4);
        a0 += scores[e0.y + h] * v0;
        a1 += scores[e1.y + h] * v1;
        a2 += scores[e2.y + h] * v2;
        a3 += scores[e3.y + h] * v3;
    }
    for (; j < end; ++j) {
        int2 e = eb[j];
        a0 += scores[e.y + h] * (*(const f32x4*)(Vb + e.x + c4 * 4));
    }
    f32x4 sum = (a0 + a1) + (a2 + a3);
    *(f32x4*)(out + (size_t)node * 128 + c4 * 4) = sum;
}

// ---------------- launcher ----------------
extern "C" void kernel_launch(void* const* d_in, const int* in_sizes, int n_in,
                              void* d_out, int out_size, void* d_ws, size_t ws_size,
                              hipStream_t stream) {
    const float* x   = (const float*)d_in[0];
    const float* ea  = (const float*)d_in[1];
    const int* eidx  = (const int*)d_in[2];
    const float* Wq  = (const float*)d_in[4];  const float* bq = (const float*)d_in[5];
    const float* Wk  = (const float*)d_in[6];  const float* bk = (const float*)d_in[7];
    const float* We  = (const float*)d_in[8];  const float* be = (const float*)d_in[9];
    const float* Wv  = (const float*)d_in[10]; const float* bv = (const float*)d_in[11];
    const int N  = in_sizes[0] / 128;
    const int NE = in_sizes[2] / 2;
    const int* srcp = eidx;
    const int* dstp = eidx + NE;
    float* out = (float*)d_out;

    char* ws = (char*)d_ws;
    size_t o = 0;
    auto alloc = [&](size_t b) { size_t r = o; o += (b + 255) & ~(size_t)255; return r; };
    float* Qb      = (float*)(ws + alloc((size_t)N * 128 * 4));
    float* Kb      = (float*)(ws + alloc((size_t)N * 128 * 4));
    float* Vb      = (float*)(ws + alloc((size_t)N * 128 * 4));
    float* scores  = (float*)(ws + alloc((size_t)NE * 8 * 4));
    short* Whi     = (short*)(ws + alloc(512 * 128 * 2));
    short* Wlo     = (short*)(ws + alloc(512 * 128 * 2));
    float* ball    = (float*)(ws + alloc(512 * 4));
    int* counts    = (int*)(ws + alloc((size_t)(N + 1) * 4));
    int* offsets   = (int*)(ws + alloc((size_t)(N + 1) * 4));
    int* cursors   = (int*)(ws + alloc((size_t)N * 4));
    int2* ebuf     = (int2*)(ws + alloc((size_t)NE * 8));
    int* partials  = (int*)(ws + alloc(64 * 4));
    (void)ws_size; (void)n_in; (void)out_size;

    (void)hipMemsetAsync(counts, 0, (size_t)(N + 1) * 4, stream);

    convert_weights<<<256, 256, 0, stream>>>(Wq, bq, Wk, bk, We, be, Wv, bv,
                                             dstp, NE, Whi, Wlo, ball, counts);

    int nb = (N + 1023) / 1024;
    scan1_kernel<<<nb, 1024, 0, stream>>>(counts, offsets, partials, N);
    scanB_kernel<<<nb, 1024, 0, stream>>>(counts, offsets, cursors, partials, N, NE);

    qkv_kernel<<<(N + 63) / 64, 256, 0, stream>>>(x, Whi, Wlo, ball, Qb, Kb, Vb, N);

    edge_kernel<<<(NE + 63) / 64, 256, 0, stream>>>(ea, srcp, dstp, Whi, Wlo, ball,
                                                    Qb, Kb, scores, cursors, ebuf, NE);

    gather_kernel<<<(N + 7) / 8, 256, 0, stream>>>(offsets, ebuf, scores, Vb, out, N);
}

// Round 9
// 351.798 us; speedup vs baseline: 1.1753x; 1.1753x over previous
//
#include <hip/hip_runtime.h>
#include <hip/hip_bf16.h>
#include <hip/hip_fp16.h>
#include <cstdint>

// Exphormer attention, MI355X.
// K1 convert weights (fp32 -> bf16 hi/lo) + dst histogram ->
// K2 scan1 + scanB (CSR offsets/cursors) ->
// K3 fused QKV projection (bf16 MFMA, weight-split) -> Q/K/V stored as f16
//    (halves the random row-gather bytes in edge + gather kernels; 0.05% err) ->
// K4 edge kernel: E proj (MFMA, f32 LDS tile) + score + CSR scatter ->
// K5 gather: out[dst] = sum score * V[src]  (f16 V rows, f32 accum)

typedef float    f32x4  __attribute__((ext_vector_type(4)));
typedef short    bf16x8 __attribute__((ext_vector_type(8)));
typedef int      i32x4  __attribute__((ext_vector_type(4)));
typedef _Float16 f16x8  __attribute__((ext_vector_type(8)));
typedef _Float16 f16x4  __attribute__((ext_vector_type(4)));

#define AP 136   // A-tile row stride (bf16 elems): 64x136x2 = 17408 B
#define EP 132   // E-tile row stride (f32 elems):  64x132x4 = 33792 B

__device__ __forceinline__ short f2bf(float f) {
    union { float f; uint32_t u; } v; v.f = f;
    uint32_t r = v.u + 0x7FFFu + ((v.u >> 16) & 1u);   // RNE
    return (short)(r >> 16);
}
__device__ __forceinline__ float bf2f(short s) {
    union { uint32_t u; float f; } v; v.u = ((uint32_t)(uint16_t)s) << 16;
    return v.f;
}
__device__ __forceinline__ int cvt2(float a, float b) {
    float2 t; t.x = a; t.y = b;
    __hip_bfloat162 h = __float22bfloat162_rn(t);
    int r; __builtin_memcpy(&r, &h, 4);
    return r;
}
// non-temporal 16B load (streaming data: don't pollute caches)
__device__ __forceinline__ float4 ntload4(const float* p) {
    i32x4 r = __builtin_nontemporal_load((const i32x4*)p);
    float4 f; __builtin_memcpy(&f, &r, 16);
    return f;
}

// ---------------- K1: weight conversion + dst histogram ----------------
// Wall rows: [0:128)=Wq, [128:256)=Wk, [256:384)=Wv, [384:512)=We
__global__ __launch_bounds__(256) void convert_weights(
        const float* __restrict__ Wq, const float* __restrict__ bq,
        const float* __restrict__ Wk, const float* __restrict__ bk,
        const float* __restrict__ We, const float* __restrict__ be,
        const float* __restrict__ Wv, const float* __restrict__ bv,
        const int* __restrict__ dstp, int NE,
        short* __restrict__ Whi, short* __restrict__ Wlo, float* __restrict__ ball,
        int* __restrict__ counts) {
    int idx = blockIdx.x * 256 + threadIdx.x;     // 0..65535
    int wrow = idx >> 7;
    int k = idx & 127;
    int which = wrow >> 7;
    int r = wrow & 127;
    const float* Wsrc = which == 0 ? Wq : which == 1 ? Wk : which == 2 ? Wv : We;
    float f = Wsrc[r * 128 + k];
    short hi = f2bf(f);
    short lo = f2bf(f - bf2f(hi));
    Whi[idx] = hi; Wlo[idx] = lo;
    if (idx < 512) {
        int wh = idx >> 7; int rr = idx & 127;
        const float* bsrc = wh == 0 ? bq : wh == 1 ? bk : wh == 2 ? bv : be;
        ball[idx] = bsrc[rr];
    }
    // fused dst histogram (grid-stride over edges)
    for (int i = idx; i < NE; i += 65536)
        atomicAdd(&counts[dstp[i]], 1);
}

// ---------------- K2: CSR scans ----------------
__global__ __launch_bounds__(1024) void scan1_kernel(const int* __restrict__ counts,
                                                     int* __restrict__ incl,
                                                     int* __restrict__ partials, int n) {
    __shared__ int sh[1024];
    int t = threadIdx.x;
    int i = blockIdx.x * 1024 + t;
    sh[t] = (i < n) ? counts[i] : 0;
    for (int off = 1; off < 1024; off <<= 1) {
        __syncthreads();
        int xv = (t >= off) ? sh[t - off] : 0;
        __syncthreads();
        sh[t] += xv;
    }
    __syncthreads();
    if (i < n) incl[i] = sh[t];
    if (t == 1023) partials[blockIdx.x] = sh[1023];
}

// fused scan2+scan3
__global__ __launch_bounds__(1024) void scanB_kernel(const int* __restrict__ counts,
                                                     int* __restrict__ offsets,
                                                     int* __restrict__ cursors,
                                                     const int* __restrict__ partials,
                                                     int n, int total) {
    int pbase = 0;
    for (int b = 0; b < (int)blockIdx.x; ++b) pbase += partials[b];
    int i = blockIdx.x * 1024 + threadIdx.x;
    if (i < n) {
        int off = offsets[i] - counts[i] + pbase;
        offsets[i] = off;
        cursors[i] = off;
    } else if (i == n) {
        offsets[n] = total;
    }
}

// ---------------- K3: fused QKV projection (f16 outputs) ----------------
__global__ __launch_bounds__(256, 4) void qkv_kernel(
        const float* __restrict__ x,
        const short* __restrict__ Whi, const short* __restrict__ Wlo,
        const float* __restrict__ ball,
        _Float16* __restrict__ Qb, _Float16* __restrict__ Kb, _Float16* __restrict__ Vb,
        int N) {
    __shared__ char lds[64 * AP * 2];
    const int t = threadIdx.x;
    const int m0 = blockIdx.x * 64;

#pragma unroll
    for (int i = 0; i < 4; ++i) {
        int g = t + i * 256;
        int row = g >> 4, c8 = g & 15;
        int grow = m0 + row;
        float4 f0 = {0.f,0.f,0.f,0.f}, f1 = {0.f,0.f,0.f,0.f};
        if (grow < N) {
            const float* p = x + (size_t)grow * 128 + c8 * 8;
            f0 = ntload4(p); f1 = ntload4(p + 4);
        }
        int4 v;
        v.x = cvt2(f0.x, f0.y); v.y = cvt2(f0.z, f0.w);
        v.z = cvt2(f1.x, f1.y); v.w = cvt2(f1.z, f1.w);
        *(int4*)(lds + row * (AP * 2) + c8 * 16) = v;
    }
    __syncthreads();

    const int w = t >> 6, lane = t & 63;
    const int r16 = lane & 15, g16 = lane >> 4;
    const int cb = w * 32;

    for (int ct = 0; ct < 3; ++ct) {
        const int colbase = ct * 128;
        f32x4 acc[4][2];
#pragma unroll
        for (int m = 0; m < 4; ++m)
#pragma unroll
            for (int n = 0; n < 2; ++n) acc[m][n] = (f32x4){0.f,0.f,0.f,0.f};

#pragma unroll
        for (int ks = 0; ks < 4; ++ks) {
            bf16x8 a[4];
#pragma unroll
            for (int m = 0; m < 4; ++m)
                a[m] = *(const bf16x8*)(lds + (m * 16 + r16) * (AP * 2) + ks * 64 + g16 * 16);
            bf16x8 bh2[2], bl2[2];
#pragma unroll
            for (int n = 0; n < 2; ++n) {
                int colg = colbase + cb + n * 16 + r16;
                bh2[n] = *(const bf16x8*)(Whi + colg * 128 + ks * 32 + g16 * 8);
                bl2[n] = *(const bf16x8*)(Wlo + colg * 128 + ks * 32 + g16 * 8);
            }
#pragma unroll
            for (int m = 0; m < 4; ++m)
#pragma unroll
                for (int n = 0; n < 2; ++n) {
                    acc[m][n] = __builtin_amdgcn_mfma_f32_16x16x32_bf16(a[m], bh2[n], acc[m][n], 0, 0, 0);
                    acc[m][n] = __builtin_amdgcn_mfma_f32_16x16x32_bf16(a[m], bl2[n], acc[m][n], 0, 0, 0);
                }
        }
        float bias[2];
#pragma unroll
        for (int n = 0; n < 2; ++n) bias[n] = ball[colbase + cb + n * 16 + r16];

        _Float16* outb = ct == 0 ? Qb : ct == 1 ? Kb : Vb;
#pragma unroll
        for (int m = 0; m < 4; ++m) {
            int grow = m0 + m * 16 + g16 * 4;
#pragma unroll
            for (int r = 0; r < 4; ++r) {
                if (grow + r < N) {
#pragma unroll
                    for (int n = 0; n < 2; ++n)
                        outb[(size_t)(grow + r) * 128 + cb + n * 16 + r16] =
                            (_Float16)(acc[m][n][r] + bias[n]);
                }
            }
        }
    }
}

// ---------------- K4: edge kernel (E proj + score + CSR scatter) ----------------
// f16 K/Q rows: 256B per row -> half the gather bytes + half the load count.
__global__ __launch_bounds__(256) void edge_kernel(
        const float* __restrict__ ea,
        const int* __restrict__ srcp, const int* __restrict__ dstp,
        const short* __restrict__ Whi, const short* __restrict__ Wlo,
        const float* __restrict__ ball,
        const _Float16* __restrict__ Qb, const _Float16* __restrict__ Kb,
        float* __restrict__ scores, int* __restrict__ cursors,
        int2* __restrict__ ebuf, int NE) {
    __shared__ char lds[64 * EP * 4];             // A-tile (bf16) unioned with E f32 tile
    const int t = threadIdx.x;
    const int e0 = blockIdx.x * 64;

    // ---- top: edge indices + fused CSR scatter ----
    int sArr[2], dArr[2];
#pragma unroll
    for (int it = 0; it < 2; ++it) {
        int task = t + it * 256;                  // 0..511
        int el = task >> 3, h = task & 7;
        int eg = e0 + el;
        bool ok = eg < NE;
        int s = ok ? srcp[eg] : 0;
        int d = ok ? dstp[eg] : 0;
        sArr[it] = s; dArr[it] = d;
        if (ok && h == 0) {
            int pos = atomicAdd(&cursors[d], 1);
            int2 v; v.x = s * 128; v.y = eg * 8;
            ebuf[pos] = v;
        }
    }

    // ---- stage ea tile -> bf16 LDS ----
#pragma unroll
    for (int i = 0; i < 4; ++i) {
        int g = t + i * 256;
        int row = g >> 4, c8 = g & 15;
        int grow = e0 + row;
        float4 f0 = {0.f,0.f,0.f,0.f}, f1 = {0.f,0.f,0.f,0.f};
        if (grow < NE) {
            const float* p = ea + (size_t)grow * 128 + c8 * 8;
            f0 = ntload4(p); f1 = ntload4(p + 4);
        }
        int4 v;
        v.x = cvt2(f0.x, f0.y); v.y = cvt2(f0.z, f0.w);
        v.z = cvt2(f1.x, f1.y); v.w = cvt2(f1.z, f1.w);
        *(int4*)(lds + row * (AP * 2) + c8 * 16) = v;
    }
    __syncthreads();

    const int w = t >> 6, lane = t & 63;
    const int r16 = lane & 15, g16 = lane >> 4;
    const int cb = w * 32;

    f32x4 acc[4][2];
#pragma unroll
    for (int m = 0; m < 4; ++m)
#pragma unroll
        for (int n = 0; n < 2; ++n) acc[m][n] = (f32x4){0.f,0.f,0.f,0.f};

#pragma unroll
    for (int ks = 0; ks < 4; ++ks) {
        bf16x8 a[4];
#pragma unroll
        for (int m = 0; m < 4; ++m)
            a[m] = *(const bf16x8*)(lds + (m * 16 + r16) * (AP * 2) + ks * 64 + g16 * 16);
        bf16x8 bh2[2], bl2[2];
#pragma unroll
        for (int n = 0; n < 2; ++n) {
            int colg = 384 + cb + n * 16 + r16;   // We rows
            bh2[n] = *(const bf16x8*)(Whi + colg * 128 + ks * 32 + g16 * 8);
            bl2[n] = *(const bf16x8*)(Wlo + colg * 128 + ks * 32 + g16 * 8);
        }
#pragma unroll
        for (int m = 0; m < 4; ++m)
#pragma unroll
            for (int n = 0; n < 2; ++n) {
                acc[m][n] = __builtin_amdgcn_mfma_f32_16x16x32_bf16(a[m], bh2[n], acc[m][n], 0, 0, 0);
                acc[m][n] = __builtin_amdgcn_mfma_f32_16x16x32_bf16(a[m], bl2[n], acc[m][n], 0, 0, 0);
            }
    }
    float bias[2];
#pragma unroll
    for (int n = 0; n < 2; ++n) bias[n] = ball[384 + cb + n * 16 + r16];

    __syncthreads();                              // all waves done reading A-tile
    float* e_lds = (float*)lds;                   // reuse as f32 E tile [64][EP]
#pragma unroll
    for (int m = 0; m < 4; ++m)
#pragma unroll
        for (int n = 0; n < 2; ++n)
#pragma unroll
            for (int r = 0; r < 4; ++r) {
                int row = m * 16 + g16 * 4 + r;
                int col = cb + n * 16 + r16;
                e_lds[row * EP + col] = acc[m][n][r] + bias[n];
            }
    __syncthreads();

    // ---- epilogue: dot(E, K*Q)*scale, clamp, exp.  f16 K/Q: 2+2 16B loads ----
#pragma unroll
    for (int it = 0; it < 2; ++it) {
        int task = t + it * 256;
        int el = task >> 3, h = task & 7;
        int eg = e0 + el;
        if (eg < NE) {
            const f16x8* Kp = (const f16x8*)(Kb + (size_t)sArr[it] * 128 + h * 16);
            const f16x8* Qp = (const f16x8*)(Qb + (size_t)dArr[it] * 128 + h * 16);
            f16x8 k0 = Kp[0], k1 = Kp[1];
            f16x8 q0 = Qp[0], q1 = Qp[1];
            float dot = 0.f;
#pragma unroll
            for (int j = 0; j < 2; ++j) {
                f32x4 ev0 = *(const f32x4*)(e_lds + el * EP + h * 16 + j * 8);
                f32x4 ev1 = *(const f32x4*)(e_lds + el * EP + h * 16 + j * 8 + 4);
                const f16x8& kk = j == 0 ? k0 : k1;
                const f16x8& qq = j == 0 ? q0 : q1;
#pragma unroll
                for (int r = 0; r < 4; ++r) {
                    dot += ev0[r] * (float)kk[r] * (float)qq[r];
                    dot += ev1[r] * (float)kk[r + 4] * (float)qq[r + 4];
                }
            }
            float sv = fminf(fmaxf(dot * 0.25f, -5.0f), 5.0f);
            scores[(size_t)eg * 8 + h] = __expf(sv);
        }
    }
}

// ---------------- K5: gather/aggregate (f16 V rows) ----------------
// 32 threads per node (f16x4 = 8B per thread), 8 nodes per block, 8-deep unroll.
__global__ __launch_bounds__(256) void gather_kernel(
        const int* __restrict__ offsets, const int2* __restrict__ eb,
        const float* __restrict__ scores, const _Float16* __restrict__ Vb,
        float* __restrict__ out, int N) {
    int node = blockIdx.x * 8 + (threadIdx.x >> 5);
    int c4 = threadIdx.x & 31;                    // 4-col slot: cols [c4*4, c4*4+4)
    if (node >= N) return;
    int h = c4 >> 2;                              // head for these 4 cols
    int beg = offsets[node], end = offsets[node + 1];
    f32x4 a0 = {0.f,0.f,0.f,0.f}, a1 = a0, a2 = a0, a3 = a0;
    int j = beg;
    auto vload = [&](int off) -> f32x4 {
        f16x4 v = *(const f16x4*)(Vb + off + c4 * 4);
        return (f32x4){(float)v[0], (float)v[1], (float)v[2], (float)v[3]};
    };
    for (; j + 8 <= end; j += 8) {
        int2 e0 = eb[j],     e1 = eb[j + 1], e2 = eb[j + 2], e3 = eb[j + 3];
        int2 e4 = eb[j + 4], e5 = eb[j + 5], e6 = eb[j + 6], e7 = eb[j + 7];
        f32x4 v0 = vload(e0.x), v1 = vload(e1.x), v2 = vload(e2.x), v3 = vload(e3.x);
        f32x4 v4 = vload(e4.x), v5 = vload(e5.x), v6 = vload(e6.x), v7 = vload(e7.x);
        a0 += scores[e0.y + h] * v0;
        a1 += scores[e1.y + h] * v1;
        a2 += scores[e2.y + h] * v2;
        a3 += scores[e3.y + h] * v3;
        a0 += scores[e4.y + h] * v4;
        a1 += scores[e5.y + h] * v5;
        a2 += scores[e6.y + h] * v6;
        a3 += scores[e7.y + h] * v7;
    }
    for (; j + 4 <= end; j += 4) {
        int2 e0 = eb[j], e1 = eb[j + 1], e2 = eb[j + 2], e3 = eb[j + 3];
        f32x4 v0 = vload(e0.x), v1 = vload(e1.x), v2 = vload(e2.x), v3 = vload(e3.x);
        a0 += scores[e0.y + h] * v0;
        a1 += scores[e1.y + h] * v1;
        a2 += scores[e2.y + h] * v2;
        a3 += scores[e3.y + h] * v3;
    }
    for (; j < end; ++j) {
        int2 e = eb[j];
        a0 += scores[e.y + h] * vload(e.x);
    }
    f32x4 sum = (a0 + a1) + (a2 + a3);
    *(f32x4*)(out + (size_t)node * 128 + c4 * 4) = sum;
}

// ---------------- launcher ----------------
extern "C" void kernel_launch(void* const* d_in, const int* in_sizes, int n_in,
                              void* d_out, int out_size, void* d_ws, size_t ws_size,
                              hipStream_t stream) {
    const float* x   = (const float*)d_in[0];
    const float* ea  = (const float*)d_in[1];
    const int* eidx  = (const int*)d_in[2];
    const float* Wq  = (const float*)d_in[4];  const float* bq = (const float*)d_in[5];
    const float* Wk  = (const float*)d_in[6];  const float* bk = (const float*)d_in[7];
    const float* We  = (const float*)d_in[8];  const float* be = (const float*)d_in[9];
    const float* Wv  = (const float*)d_in[10]; const float* bv = (const float*)d_in[11];
    const int N  = in_sizes[0] / 128;
    const int NE = in_sizes[2] / 2;
    const int* srcp = eidx;
    const int* dstp = eidx + NE;
    float* out = (float*)d_out;

    char* ws = (char*)d_ws;
    size_t o = 0;
    auto alloc = [&](size_t b) { size_t r = o; o += (b + 255) & ~(size_t)255; return r; };
    _Float16* Qb   = (_Float16*)(ws + alloc((size_t)N * 128 * 2));
    _Float16* Kb   = (_Float16*)(ws + alloc((size_t)N * 128 * 2));
    _Float16* Vb   = (_Float16*)(ws + alloc((size_t)N * 128 * 2));
    float* scores  = (float*)(ws + alloc((size_t)NE * 8 * 4));
    short* Whi     = (short*)(ws + alloc(512 * 128 * 2));
    short* Wlo     = (short*)(ws + alloc(512 * 128 * 2));
    float* ball    = (float*)(ws + alloc(512 * 4));
    int* counts    = (int*)(ws + alloc((size_t)(N + 1) * 4));
    int* offsets   = (int*)(ws + alloc((size_t)(N + 1) * 4));
    int* cursors   = (int*)(ws + alloc((size_t)N * 4));
    int2* ebuf     = (int2*)(ws + alloc((size_t)NE * 8));
    int* partials  = (int*)(ws + alloc(64 * 4));
    (void)ws_size; (void)n_in; (void)out_size;

    (void)hipMemsetAsync(counts, 0, (size_t)(N + 1) * 4, stream);

    convert_weights<<<256, 256, 0, stream>>>(Wq, bq, Wk, bk, We, be, Wv, bv,
                                             dstp, NE, Whi, Wlo, ball, counts);

    int nb = (N + 1023) / 1024;
    scan1_kernel<<<nb, 1024, 0, stream>>>(counts, offsets, partials, N);
    scanB_kernel<<<nb, 1024, 0, stream>>>(counts, offsets, cursors, partials, N, NE);

    qkv_kernel<<<(N + 63) / 64, 256, 0, stream>>>(x, Whi, Wlo, ball, Qb, Kb, Vb, N);

    edge_kernel<<<(NE + 63) / 64, 256, 0, stream>>>(ea, srcp, dstp, Whi, Wlo, ball,
                                                    Qb, Kb, scores, cursors, ebuf, NE);

    gather_kernel<<<(N + 7) / 8, 256, 0, stream>>>(offsets, ebuf, scores, Vb, out, N);
}